// Round 3
// 1499.677 us; speedup vs baseline: 1.1665x; 1.1665x over previous
//
#include <hip/hip_runtime.h>

typedef unsigned short u16;
typedef unsigned int   u32;
typedef __attribute__((ext_vector_type(8))) short bf16x8;
typedef __attribute__((ext_vector_type(4))) float f32x4;

__device__ __forceinline__ u16 f2b(float f) {
  union { float f; u32 u; } x; x.f = f;
  u32 r = x.u + 0x7FFFu + ((x.u >> 16) & 1u);
  return (u16)(r >> 16);
}
__device__ __forceinline__ float b2f(u16 b) {
  union { u32 u; float f; } x; x.u = ((u32)b) << 16;
  return x.f;
}

#define GAS(p) ((const __attribute__((address_space(1))) void*)(p))
#define LAS(p) ((__attribute__((address_space(3))) void*)(p))

// XCD-aware bijective swizzle (m204) + GROUP_M=8 grouped walk for L2/L3 locality.
// Requires gridDim.x*gridDim.y % 8 == 0 (true for all launches here).
__device__ __forceinline__ void swizzle_mn(int& mtile, int& ntile) {
  const int nwg_n = gridDim.x, nwg_m = gridDim.y;
  const int flat = blockIdx.y * nwg_n + blockIdx.x;
  const int per = (nwg_m * nwg_n) >> 3;          // blocks per XCD chunk
  const int sw = (flat & 7) * per + (flat >> 3); // contiguous chunk per XCD
  const int GM = 8;
  const int nig = GM * nwg_n;                    // blocks per group
  const int gid = sw / nig;
  const int first_m = gid * GM;
  int gsz = nwg_m - first_m; if (gsz > GM) gsz = GM;
  const int rem = sw - gid * nig;
  mtile = first_m + rem % gsz;                   // m fastest -> B panel L2-hot
  ntile = rem / gsz;
}

// ---------------- cast fp32 -> bf16, 8 elems/thread ----------------
__global__ __launch_bounds__(256) void cast_bf16(const float* __restrict__ in,
                                                 u16* __restrict__ out, int n8) {
  int i = blockIdx.x * 256 + threadIdx.x;
  if (i >= n8) return;
  const float4* p = (const float4*)(in + (size_t)i * 8);
  float4 a = p[0], b = p[1];
  bf16x8 o;
  o[0] = (short)f2b(a.x); o[1] = (short)f2b(a.y); o[2] = (short)f2b(a.z); o[3] = (short)f2b(a.w);
  o[4] = (short)f2b(b.x); o[5] = (short)f2b(b.y); o[6] = (short)f2b(b.z); o[7] = (short)f2b(b.w);
  *(bf16x8*)(out + (size_t)i * 8) = o;
}

// ---------------- fused NT GEMM over B = [Wv; Wr; Wq] (N = 8704) ----------------
// n in [0,4096)      -> vs   (bf16)
// n in [4096,8192)   -> sigmoid(x) fp32 into d_out (gate, later overwritten)
// n in [8192,8704)   -> qs   (bf16, row stride 512)
__global__ __launch_bounds__(256, 4) void gemm_fused(const u16* __restrict__ A,
                                                     const u16* __restrict__ B,
                                                     u16* __restrict__ vs,
                                                     float* __restrict__ sig,
                                                     u16* __restrict__ qs,
                                                     int K) {
  __shared__ u16 As[128 * 32];
  __shared__ u16 Bs[128 * 32];
  const int tid = threadIdx.x;
  const int wave = tid >> 6, lane = tid & 63;
  const int quad = lane >> 4, l15 = lane & 15;
  int mtile, ntile;
  swizzle_mn(mtile, ntile);
  const int m0 = mtile * 128, n0 = ntile * 128;
  const int wr = (wave >> 1) * 64, wc = (wave & 1) * 64;

  f32x4 acc[4][4] = {};

  const int srow = wave * 16 + (lane >> 2);
  const int scol = (lane & 3) * 8;
  const u16* gA = A + (size_t)(m0 + srow) * K + scol;
  const u16* gA2 = gA + (size_t)64 * K;
  const u16* gB = B + (size_t)(n0 + srow) * K + scol;
  const u16* gB2 = gB + (size_t)64 * K;
  u16* lA = As + wave * 512;
  u16* lB = Bs + wave * 512;
  const u16* aAddr = As + (wr + l15) * 32 + quad * 8;
  const u16* bAddr = Bs + (wc + l15) * 32 + quad * 8;

  for (int kk = 0; kk < K; kk += 32) {
    __builtin_amdgcn_global_load_lds(GAS(gA + kk),  LAS(lA),        16, 0, 0);
    __builtin_amdgcn_global_load_lds(GAS(gA2 + kk), LAS(lA + 2048), 16, 0, 0);
    __builtin_amdgcn_global_load_lds(GAS(gB + kk),  LAS(lB),        16, 0, 0);
    __builtin_amdgcn_global_load_lds(GAS(gB2 + kk), LAS(lB + 2048), 16, 0, 0);
    __syncthreads();
    bf16x8 af[4], bfr[4];
#pragma unroll
    for (int t = 0; t < 4; ++t) {
      af[t]  = *(const bf16x8*)(aAddr + t * 512);
      bfr[t] = *(const bf16x8*)(bAddr + t * 512);
    }
#pragma unroll
    for (int i = 0; i < 4; ++i)
#pragma unroll
      for (int j = 0; j < 4; ++j)
        acc[i][j] = __builtin_amdgcn_mfma_f32_16x16x32_bf16(af[i], bfr[j], acc[i][j], 0, 0, 0);
    __syncthreads();
  }

#pragma unroll
  for (int i = 0; i < 4; ++i)
#pragma unroll
    for (int j = 0; j < 4; ++j)
#pragma unroll
      for (int r = 0; r < 4; ++r) {
        int row = m0 + wr + i * 16 + quad * 4 + r;
        int col = n0 + wc + j * 16 + l15;
        float v = acc[i][j][r];
        if (n0 < 4096) {
          vs[(size_t)row * 4096 + col] = f2b(v);
        } else if (n0 < 8192) {
          sig[(size_t)row * 4096 + (col - 4096)] = 1.0f / (1.0f + __expf(-v));
        } else {
          qs[(size_t)row * 512 + (col - 8192)] = f2b(v);
        }
      }
}

// ---------------- generic NT GEMM ----------------
// EPI 0: bf16 store. EPI 2: fp32 store of acc*gate[idx] (gate = precomputed sigmoid).
template <int EPI>
__global__ __launch_bounds__(256, 4) void gemm_nt(const u16* __restrict__ A,
                                                  const u16* __restrict__ B,
                                                  void* __restrict__ C,
                                                  const float* __restrict__ gate,
                                                  int M, int N, int K) {
  __shared__ u16 As[128 * 32];
  __shared__ u16 Bs[128 * 32];
  const int tid = threadIdx.x;
  const int wave = tid >> 6, lane = tid & 63;
  const int quad = lane >> 4, l15 = lane & 15;
  int mtile, ntile;
  swizzle_mn(mtile, ntile);
  const int m0 = mtile * 128, n0 = ntile * 128;
  const int wr = (wave >> 1) * 64, wc = (wave & 1) * 64;

  f32x4 acc[4][4] = {};

  const int srow = wave * 16 + (lane >> 2);
  const int scol = (lane & 3) * 8;
  const u16* gA = A + (size_t)(m0 + srow) * K + scol;
  const u16* gA2 = gA + (size_t)64 * K;
  const u16* gB = B + (size_t)(n0 + srow) * K + scol;
  const u16* gB2 = gB + (size_t)64 * K;
  u16* lA = As + wave * 512;
  u16* lB = Bs + wave * 512;
  const u16* aAddr = As + (wr + l15) * 32 + quad * 8;
  const u16* bAddr = Bs + (wc + l15) * 32 + quad * 8;

  for (int kk = 0; kk < K; kk += 32) {
    __builtin_amdgcn_global_load_lds(GAS(gA + kk),  LAS(lA),        16, 0, 0);
    __builtin_amdgcn_global_load_lds(GAS(gA2 + kk), LAS(lA + 2048), 16, 0, 0);
    __builtin_amdgcn_global_load_lds(GAS(gB + kk),  LAS(lB),        16, 0, 0);
    __builtin_amdgcn_global_load_lds(GAS(gB2 + kk), LAS(lB + 2048), 16, 0, 0);
    __syncthreads();
    bf16x8 af[4], bfr[4];
#pragma unroll
    for (int t = 0; t < 4; ++t) {
      af[t]  = *(const bf16x8*)(aAddr + t * 512);
      bfr[t] = *(const bf16x8*)(bAddr + t * 512);
    }
#pragma unroll
    for (int i = 0; i < 4; ++i)
#pragma unroll
      for (int j = 0; j < 4; ++j)
        acc[i][j] = __builtin_amdgcn_mfma_f32_16x16x32_bf16(af[i], bfr[j], acc[i][j], 0, 0, 0);
    __syncthreads();
  }

#pragma unroll
  for (int i = 0; i < 4; ++i)
#pragma unroll
    for (int j = 0; j < 4; ++j)
#pragma unroll
      for (int r = 0; r < 4; ++r) {
        int row = m0 + wr + i * 16 + quad * 4 + r;
        int col = n0 + wc + j * 16 + l15;
        size_t idx = (size_t)row * N + col;
        float v = acc[i][j][r];
        if (EPI == 0) {
          ((u16*)C)[idx] = f2b(v);
        } else {
          ((float*)C)[idx] = v * gate[idx];
        }
      }
}

// ---------------- RoPE: in-place q (pos 64+rho) and k-hi; k-lo into krl[64+r] ----------------
__global__ __launch_bounds__(256) void rope_kernel(u16* __restrict__ q,
                                                   u16* __restrict__ k,
                                                   u16* __restrict__ krl) {
  const int r = blockIdx.x;     // token row 0..8191
  const int p = threadIdx.x;    // pair index 0..255
  const int rho = r & 63;
  const float inv = __expf((float)p * (-2.0f / 512.0f) * 9.210340371976184f); // 10000^(-2p/512)
  const float ah = (float)(64 + rho) * inv;
  const float al = (float)rho * inv;
  const float ch = cosf(ah), sh = sinf(ah);
  const float cl = cosf(al), sl = sinf(al);
  const size_t base = (size_t)r * 512 + 2 * p;
  float q0 = b2f(q[base]), q1 = b2f(q[base + 1]);
  q[base]     = f2b(q0 * ch - q1 * sh);
  q[base + 1] = f2b(q1 * ch + q0 * sh);
  float k0 = b2f(k[base]), k1 = b2f(k[base + 1]);
  k[base]     = f2b(k0 * ch - k1 * sh);
  k[base + 1] = f2b(k1 * ch + k0 * sh);
  const size_t lbase = base + (size_t)64 * 512;
  krl[lbase]     = f2b(k0 * cl - k1 * sl);
  krl[lbase + 1] = f2b(k1 * cl + k0 * sl);
}

// ---------------- zero pads: krl rows [0,64) and vT cols [0,64) ----------------
__global__ __launch_bounds__(256) void zero_pads(u16* __restrict__ krl, u16* __restrict__ vT) {
  int i = blockIdx.x * 256 + threadIdx.x;
  if (i < 64 * 512) krl[i] = 0;
  if (i < 4096 * 64) {
    int row = i >> 6, col = i & 63;
    vT[(size_t)row * 8256 + col] = 0;
  }
}

// ---------------- transpose v (8192x4096) -> vT (4096 x 8256), col offset 64 ----------------
__global__ __launch_bounds__(256) void transpose_v(const u16* __restrict__ v, u16* __restrict__ vT) {
  __shared__ u16 tl[64 * 72];  // [n][t], pad to 72 for aligned b128 reads
  const int n0 = blockIdx.x * 64, t0 = blockIdx.y * 64;
  const int tid = threadIdx.x;
  const int cg = tid & 7;    // 8-element group
  const int rr = tid >> 3;   // 0..31
#pragma unroll
  for (int j = 0; j < 2; ++j) {
    int trow = j * 32 + rr;
    bf16x8 x = *(const bf16x8*)(v + (size_t)(t0 + trow) * 4096 + n0 + cg * 8);
#pragma unroll
    for (int e = 0; e < 8; ++e) tl[(cg * 8 + e) * 72 + trow] = (u16)x[e];
  }
  __syncthreads();
#pragma unroll
  for (int j = 0; j < 2; ++j) {
    int nrow = j * 32 + rr;
    bf16x8 y = *(const bf16x8*)(tl + nrow * 72 + cg * 8);
    *(bf16x8*)(vT + (size_t)(n0 + nrow) * 8256 + 64 + t0 + cg * 8) = y;
  }
}

// ---------------- fused chunked attention ----------------
__global__ __launch_bounds__(256) void attn_kernel(const u16* __restrict__ qr,
                                                   const u16* __restrict__ krl,
                                                   const u16* __restrict__ khi,
                                                   const u16* __restrict__ vT,
                                                   u16* __restrict__ ys) {
  __shared__ float S[64][129];
  __shared__ u16 Abuf[64][136];
  const int s = blockIdx.x, c = blockIdx.y;
  const int tid = threadIdx.x;
  const int wave = tid >> 6, lane = tid & 63;
  const int quad = lane >> 4, l15 = lane & 15;

  // ---- phase 1: S = q @ k_window^T ----
  f32x4 sc[8] = {};
  const u16* qrow = qr + (size_t)(c * 64 + wave * 16 + l15) * 512 + quad * 8;
  const u16* bbase[8];
#pragma unroll
  for (int nt = 0; nt < 8; ++nt) {
    int n = nt * 16 + l15;
    bbase[nt] = (nt < 4) ? (krl + (size_t)(c * 64 + n) * 512 + quad * 8)
                         : (khi + (size_t)(c * 64 + (n - 64)) * 512 + quad * 8);
  }
  for (int kt = 0; kt < 16; ++kt) {
    bf16x8 a = *(const bf16x8*)(qrow + kt * 32);
#pragma unroll
    for (int nt = 0; nt < 8; ++nt) {
      bf16x8 b = *(const bf16x8*)(bbase[nt] + kt * 32);
      sc[nt] = __builtin_amdgcn_mfma_f32_16x16x32_bf16(a, b, sc[nt], 0, 0, 0);
    }
  }
  const float SCALE = 0.04419417382415922f;  // 1/sqrt(512)
#pragma unroll
  for (int nt = 0; nt < 8; ++nt)
#pragma unroll
    for (int r = 0; r < 4; ++r)
      S[wave * 16 + quad * 4 + r][nt * 16 + l15] = sc[nt][r] * SCALE;
  __syncthreads();

  // ---- softmax: row i valid over j <= i+64; invalid -> 0 ----
  if (tid < 64) {
    const int i = tid, lim = i + 64;
    float mx = -1e30f;
    for (int j = 0; j <= lim; ++j) mx = fmaxf(mx, S[i][j]);
    float sum = 0.f;
    for (int j = 0; j <= lim; ++j) sum += __expf(S[i][j] - mx);
    float invs = 1.f / sum;
    for (int j = 0; j < 128; ++j)
      Abuf[i][j] = (j <= lim) ? f2b(__expf(S[i][j] - mx) * invs) : (u16)0;
  }
  __syncthreads();

  // ---- phase 2: O = A @ V ----
  const int rowA = wave * 16 + l15;
  const size_t vcol = (size_t)c * 64;
  for (int nc = 0; nc < 8; ++nc) {
    const int n0 = s * 1024 + nc * 128;
    f32x4 o[8] = {};
#pragma unroll
    for (int kt = 0; kt < 4; ++kt) {
      bf16x8 a = *(const bf16x8*)(&Abuf[rowA][kt * 32 + quad * 8]);
#pragma unroll
      for (int nt = 0; nt < 8; ++nt) {
        const u16* vp = vT + (size_t)(n0 + nt * 16 + l15) * 8256 + vcol + kt * 32 + quad * 8;
        bf16x8 b = *(const bf16x8*)vp;
        o[nt] = __builtin_amdgcn_mfma_f32_16x16x32_bf16(a, b, o[nt], 0, 0, 0);
      }
    }
#pragma unroll
    for (int nt = 0; nt < 8; ++nt)
#pragma unroll
      for (int r = 0; r < 4; ++r)
        ys[(size_t)(c * 64 + wave * 16 + quad * 4 + r) * 4096 + n0 + nt * 16 + l15] =
            f2b(o[nt][r]);
  }
}

// ---------------- host ----------------
extern "C" void kernel_launch(void* const* d_in, const int* in_sizes, int n_in,
                              void* d_out, int out_size, void* d_ws, size_t ws_size,
                              hipStream_t stream) {
  (void)in_sizes; (void)n_in; (void)out_size; (void)ws_size;
  const float* xs = (const float*)d_in[0];
  const float* Wq = (const float*)d_in[1];
  const float* Wk = (const float*)d_in[2];
  const float* Wv = (const float*)d_in[3];
  const float* Wo = (const float*)d_in[4];
  const float* Wr = (const float*)d_in[5];

  char* ws = (char*)d_ws;
  size_t off = 0;
  auto alloc = [&](size_t elems) {
    u16* p = (u16*)(ws + off);
    off += ((elems * 2 + 255) & ~(size_t)255);
    return p;
  };
  u16* xs_b   = alloc((size_t)8192 * 4096);
  u16* Bf     = alloc((size_t)8704 * 4096);  // [Wv(4096); Wr(4096); Wq(512)] rows
  u16* Wk_b   = alloc((size_t)512 * 512);
  u16* Wo_b   = alloc((size_t)4096 * 4096);
  u16* qs_raw = alloc((size_t)8192 * 512);   // becomes q_rope in-place
  u16* ks_raw = alloc((size_t)8192 * 512);   // becomes k_hi in-place
  u16* krl    = alloc((size_t)8256 * 512);   // k_lo with 64 zero rows in front
  u16* vs_b   = alloc((size_t)8192 * 4096);  // later reused as ys
  u16* vT     = alloc((size_t)4096 * 8256);
  u16* ys     = vs_b;
  u16* Wv_b   = Bf;
  u16* Wr_b   = Bf + (size_t)4096 * 4096;
  u16* Wq_b   = Bf + (size_t)8192 * 4096;

  auto cast = [&](const float* in, u16* out, size_t n) {
    int n8 = (int)(n / 8);
    cast_bf16<<<(n8 + 255) / 256, 256, 0, stream>>>(in, out, n8);
  };
  cast(xs, xs_b, (size_t)8192 * 4096);
  cast(Wv, Wv_b, (size_t)4096 * 4096);
  cast(Wr, Wr_b, (size_t)4096 * 4096);
  cast(Wq, Wq_b, (size_t)512 * 4096);
  cast(Wk, Wk_b, (size_t)512 * 512);
  cast(Wo, Wo_b, (size_t)4096 * 4096);

  // fused: vs = xs@Wv.T (bf16), sigma = sigmoid(xs@Wr.T) -> d_out (fp32), qs = xs@Wq.T (bf16)
  gemm_fused<<<dim3(68, 64), 256, 0, stream>>>(xs_b, Bf, vs_b, (float*)d_out, qs_raw, 4096);
  // ks = qs @ Wk.T  (8192 x 512)
  gemm_nt<0><<<dim3(4, 64), 256, 0, stream>>>(qs_raw, Wk_b, ks_raw, nullptr, 8192, 512, 512);
  // RoPE (in-place q, k_hi; k_lo -> krl+64 rows)
  rope_kernel<<<8192, 256, 0, stream>>>(qs_raw, ks_raw, krl);
  zero_pads<<<1024, 256, 0, stream>>>(krl, vT);
  // vT = transpose(vs) with +64 col offset
  transpose_v<<<dim3(64, 128), 256, 0, stream>>>(vs_b, vT);
  // attention -> ys (reuses vs_b storage; vT already built)
  attn_kernel<<<dim3(4, 128), 256, 0, stream>>>(qs_raw, krl, ks_raw, vT, ys);
  // out = (ys @ Wo.T) * sigma
  gemm_nt<2><<<dim3(32, 64), 256, 0, stream>>>(ys, Wo_b, d_out, (const float*)d_out,
                                               8192, 4096, 4096);
}